// Round 13
// baseline (176.054 us; speedup 1.0000x reference)
//
#include <hip/hip_runtime.h>
#include <hip/hip_bf16.h>
#include <stdint.h>

#define DEV __device__ __forceinline__

typedef unsigned short u16;
typedef unsigned int u32;
typedef short bh8 __attribute__((ext_vector_type(8)));
typedef float f32x4 __attribute__((ext_vector_type(4)));

// ---------- bf16 helpers ----------
// Software f2bf (RNE) for cold paths (prep/ln) — unchanged rounding vs all passing rounds.
DEV float bf2f(u16 v){ return __uint_as_float(((u32)v)<<16); }
DEV u16 f2bf(float f){
    u32 x = __float_as_uint(f);
    x += 0x7fffu + ((x>>16)&1u);
    return (u16)(x>>16);
}
// Hot-path conversions via hip_bf16 API (RNE, same as f2bf). R13: per m240 the
// COMPILER lowers these to v_cvt_pk_bf16_f32 on gfx950 — the sanctioned path
// (R4's hand-written asm was the mistake). No inline asm.
DEV u32 pk2h(float a, float b){
    float2 t; t.x = a; t.y = b;
    __hip_bfloat162 h = __float22bfloat162_rn(t);
    union{ __hip_bfloat162 h; u32 u; } c; c.h = h; return c.u;
}
DEV u16 f2bfh(float f){
    __hip_bfloat16 h = __float2bfloat16(f);
    union{ __hip_bfloat16 h; u16 u; } c; c.h = h; return c.u;
}
DEV int2 pk4(float a, float b, float c, float d){
    int2 r;
    r.x = (int)pk2h(a, b);
    r.y = (int)pk2h(c, d);
    return r;
}
DEV bh8 ld_frag(const u16* p){
    int4 v = *(const int4*)p;
    union{ int4 i; bh8 h; } u; u.i = v; return u.h;
}
#define MFMA __builtin_amdgcn_mfma_f32_16x16x32_bf16

// Problem constants: BSZ=1, S=256, C=128, H=4, D=32, F=64. f32 I/O, bf16 internal.
//
// Session ledger:
//  R0: 4 kernels, mega 46.0, total 182.7
//  R1-R3,R11: occupancy chase (3 blocks/CU, 512-thr): all slower. mega is
//      barrier/serial-chain-bound at 4 waves x 4mt; R8 body is the optimum shape.
//  R4: hand-written asm cvt_pk -> NaN. FAILED (API-path casts are fine, see R13).
//  R5/R6/R7/R9/R10: five LN-fusion variants failed. ln stays separate.
//  R8: prep if-chain + oproj direct-store: mega 45.1, total 175.8
//  R12: prep+ln merged, ln grid-strided: total 174.4. Launch overhead ~1-5us =>
//      non-mega pool is mostly fixed harness overhead + near-floor small kernels.
//  R13 (this): mega VALU cut — epilogue bf16 packing via __float22bfloat162_rn
//      (compiler emits v_cvt_pk_bf16_f32; ~24 pk4 x ~16 ops -> ~2 ops each) +
//      T5 setprio around MFMA clusters (2 blocks/CU phase-independent = m191
//      regime, +4-7% there). Decision: VALUBusy 32->~24 & mega <42 else plateau.

// Param block layout (elements, bf16) inside workspace:
#define P_LNW 0
#define P_LNB 128
#define P_QW  256
#define P_QB  16640
#define P_KW  16768
#define P_KB  33152
#define P_VW  33280
#define P_VB  49664
#define P_QFW 49792
#define P_QFB 50816
#define P_KFW 50848
#define P_KFB 51872
#define P_GW  51904
#define P_GB  68288
#define P_OW  68416
#define P_OB  84800
#define P_TOT 84928
#define P_CQW 84928    // [h][j][c] 4*32*128
#define P_CQB 101312   // [h][j]    4*32
#define P_CKW 101440
#define P_CKB 117824

#define NCONV 332
#define LN_BLOCKS 2048     // 2048 blocks x 32 tokens = 65536 tokens

// ---------------- prep + LN merged (independent work, one launch) ----------------
__global__ void prep_ln_kernel(
    const float* p0, const float* p1, const float* p2, const float* p3,
    const float* p4, const float* p5, const float* p6, const float* p7,
    const float* p8, const float* p9, const float* p10, const float* p11,
    const float* p12, const float* p13, const float* p14, const float* p15,
    u16* __restrict__ dst,
    const float* __restrict__ z, u16* __restrict__ zn){
    int b = blockIdx.x, tid = threadIdx.x;
    if(b < NCONV){
        int idx = b*256 + tid;
        if(idx >= P_TOT) return;
        // if-chain (cndmask), NOT runtime-indexed local arrays (rule #20 -> scratch).
        const float* sp = p0; int base = P_LNW;
        if(idx >= P_LNB){ sp = p1;  base = P_LNB; }
        if(idx >= P_QW ){ sp = p2;  base = P_QW;  }
        if(idx >= P_QB ){ sp = p3;  base = P_QB;  }
        if(idx >= P_KW ){ sp = p4;  base = P_KW;  }
        if(idx >= P_KB ){ sp = p5;  base = P_KB;  }
        if(idx >= P_VW ){ sp = p6;  base = P_VW;  }
        if(idx >= P_VB ){ sp = p7;  base = P_VB;  }
        if(idx >= P_QFW){ sp = p8;  base = P_QFW; }
        if(idx >= P_QFB){ sp = p9;  base = P_QFB; }
        if(idx >= P_KFW){ sp = p10; base = P_KFW; }
        if(idx >= P_KFB){ sp = p11; base = P_KFB; }
        if(idx >= P_GW ){ sp = p12; base = P_GW;  }
        if(idx >= P_GB ){ sp = p13; base = P_GB;  }
        if(idx >= P_OW ){ sp = p14; base = P_OW;  }
        if(idx >= P_OB ){ sp = p15; base = P_OB;  }
        dst[idx] = f2bf(sp[idx - base]);
    } else if(b < NCONV + 128){
        // combined weights: Wc[h][j][c] = sum_d F[j][d] * W[h*32+d][c]
        int idx = (b - NCONV)*256 + tid;            // [0, 32768)
        int sel = idx >> 14;
        int rem = idx & 16383;
        int h = rem >> 12, j = (rem >> 7) & 31, c = rem & 127;
        const float* FWp = sel ? p10 : p8;
        const float* Wp  = sel ? p4  : p2;
        float s = 0.f;
        #pragma unroll
        for(int d=0; d<32; ++d)
            s += FWp[j*32+d] * Wp[(h*32+d)*128 + c];
        dst[(sel ? P_CKW : P_CQW) + h*4096 + j*128 + c] = f2bf(s);
    } else if(b == NCONV + 128){
        // combined biases: bc[h][j] = sum_d F[j][d]*b[h*32+d] + fb[j]
        int t = tid;
        int sel = t >> 7, h = (t >> 5) & 3, j = t & 31;
        const float* FWp = sel ? p10 : p8;
        const float* FBp = sel ? p11 : p9;
        const float* Bp  = sel ? p5  : p3;
        float s = FBp[j];
        #pragma unroll
        for(int d=0; d<32; ++d)
            s += FWp[j*32+d] * Bp[h*32+d];
        dst[(sel ? P_CKB : P_CQB) + h*32 + j] = f2bf(s);
    } else {
        // ---- LayerNorm, grid-strided: 32 tokens/block, 8 per wave ----
        int lb = b - (NCONV + 129);                 // [0, LN_BLOCKS)
        int lane = tid & 63, wv = tid >> 6;
        int c0 = 2*lane;
        float w0 = p0[c0], w1 = p0[c0+1];
        float b0 = p1[c0], b1 = p1[c0+1];
        #pragma unroll 1
        for(int it=0; it<8; ++it){
            int t = lb*32 + it*4 + wv;
            float2 v = ((const float2*)z)[(size_t)t*64 + lane];
            float x0 = v.x, x1 = v.y;
            float s = x0 + x1, s2 = x0*x0 + x1*x1;
            #pragma unroll
            for(int o=1;o<64;o<<=1){ s += __shfl_xor(s,o,64); s2 += __shfl_xor(s2,o,64); }
            float mean = s*(1.f/128.f);
            float var  = s2*(1.f/128.f) - mean*mean;
            float rs = rsqrtf(var + 1e-5f);
            float o0 = (x0-mean)*rs*w0 + b0;
            float o1 = (x1-mean)*rs*w1 + b1;
            u32 po = (u32)f2bf(o0) | ((u32)f2bf(o1)<<16);
            *(u32*)(zn + (size_t)t*128 + c0) = po;
        }
    }
}

// ---------------- mega kernel: one block per (row, head) [R8 body + cvt-pk epilogues + setprio] ----------------
// LDS (bytes):
//   mask_f [256 f32]      @ 0       (1024)
//   kfT    [64][264] u16  @ 1024    (33792)  kf^T [f][n], masked
//   vT     [32][264] u16  @ 34816   (16896)  v^T [d][n] masked
//   qf     [256][68] u16  @ 1024    (34816)  aliases kfT(+vT head); [n][f]
//   kvT    [33][68]  u16  @ 51712   (4488)   kv^T [d][f]; row 32 = ksum
#define ST_N 264
#define ST_F 68
#define SM_KF   1024
#define SM_VT   34816
#define SM_QF   1024
#define SM_KVT  51712
#define SM_TOT  56200

__global__ __launch_bounds__(256,2)
void mega_kernel(const u16* __restrict__ zn, const int* __restrict__ mask,
                 const u16* __restrict__ pb, u16* __restrict__ attn){
    __shared__ __align__(16) char smem[SM_TOT];
    float* mask_f = (float*)smem;
    u16* kfT = (u16*)(smem + SM_KF);
    u16* vT  = (u16*)(smem + SM_VT);
    u16* qf  = (u16*)(smem + SM_QF);
    u16* kvT = (u16*)(smem + SM_KVT);

    int g = blockIdx.x, row = g>>2, h = g&3;
    int tid = threadIdx.x, lane = tid & 63, wv = tid >> 6;
    int lm = lane & 15, quad = lane >> 4;

    mask_f[tid] = (float)mask[row*256 + tid];

    // zn A-frags: loaded once, reused by all GEMM phases
    bh8 a[4][4];
    {
        const u16* Ab = zn + ((size_t)row*256 + wv*64 + lm)*128 + quad*8;
        #pragma unroll
        for(int mt=0; mt<4; ++mt)
            #pragma unroll
            for(int ks=0; ks<4; ++ks)
                a[mt][ks] = ld_frag(Ab + (size_t)mt*16*128 + ks*32);
    }
    bh8 onesf;
    { union{int4 i; bh8 h;} u; u.i.x=u.i.y=u.i.z=u.i.w=0x3F803F80; onesf = u.h; }

    __syncthreads();

    f32x4 gacc[4][2];
    // ---- phase 1 (merged): B = [ck0 ck1 | v0 v1 | g0 g1], shared A ----
    {
        f32x4 acc[4][6];
        #pragma unroll
        for(int mt=0;mt<4;++mt)
            #pragma unroll
            for(int j=0;j<6;++j) acc[mt][j] = (f32x4){0,0,0,0};
        __builtin_amdgcn_s_setprio(1);
        #pragma unroll
        for(int ks=0; ks<4; ++ks){
            bh8 b[6];
            b[0] = ld_frag(pb + P_CKW + h*4096 + lm*128            + ks*32 + quad*8);
            b[1] = ld_frag(pb + P_CKW + h*4096 + (16+lm)*128       + ks*32 + quad*8);
            b[2] = ld_frag(pb + P_VW + (size_t)(h*32 + lm)*128     + ks*32 + quad*8);
            b[3] = ld_frag(pb + P_VW + (size_t)(h*32 + 16+lm)*128  + ks*32 + quad*8);
            b[4] = ld_frag(pb + P_GW + (size_t)(h*32 + lm)*128     + ks*32 + quad*8);
            b[5] = ld_frag(pb + P_GW + (size_t)(h*32 + 16+lm)*128  + ks*32 + quad*8);
            #pragma unroll
            for(int mt=0; mt<4; ++mt)
                #pragma unroll
                for(int j=0;j<6;++j)
                    acc[mt][j] = MFMA(a[mt][ks], b[j], acc[mt][j], 0,0,0);
        }
        __builtin_amdgcn_s_setprio(0);
        float bk0 = bf2f(pb[P_CKB + h*32 + lm]);
        float bk1 = bf2f(pb[P_CKB + h*32 + 16 + lm]);
        float bv0 = bf2f(pb[P_VB + h*32 + lm]);
        float bv1 = bf2f(pb[P_VB + h*32 + 16 + lm]);
        float bg0 = bf2f(pb[P_GB + h*32 + lm]);
        float bg1 = bf2f(pb[P_GB + h*32 + 16 + lm]);
        #pragma unroll
        for(int mt=0; mt<4; ++mt){
            int n0 = wv*64 + mt*16 + quad*4;
            float ep0[4], em0[4], ep1[4], em1[4], v0[4], v1[4];
            #pragma unroll
            for(int r=0; r<4; ++r){
                float mk = mask_f[n0+r];
                float m0 = fminf(8.f, fmaxf(-8.f, acc[mt][0][r] + bk0));
                float m1 = fminf(8.f, fmaxf(-8.f, acc[mt][1][r] + bk1));
                ep0[r] = __expf( m0)*mk;  em0[r] = __expf(-m0)*mk;
                ep1[r] = __expf( m1)*mk;  em1[r] = __expf(-m1)*mk;
                v0[r] = (acc[mt][2][r] + bv0)*mk;
                v1[r] = (acc[mt][3][r] + bv1)*mk;
                gacc[mt][0][r] = 1.f/(1.f + __expf(-(acc[mt][4][r] + bg0)));
                gacc[mt][1][r] = 1.f/(1.f + __expf(-(acc[mt][5][r] + bg1)));
            }
            *(int2*)(kfT + (size_t)(lm   )*ST_N + n0) = pk4(ep0[0],ep0[1],ep0[2],ep0[3]);
            *(int2*)(kfT + (size_t)(lm+32)*ST_N + n0) = pk4(em0[0],em0[1],em0[2],em0[3]);
            *(int2*)(kfT + (size_t)(lm+16)*ST_N + n0) = pk4(ep1[0],ep1[1],ep1[2],ep1[3]);
            *(int2*)(kfT + (size_t)(lm+48)*ST_N + n0) = pk4(em1[0],em1[1],em1[2],em1[3]);
            *(int2*)(vT  + (size_t)(lm   )*ST_N + n0) = pk4(v0[0],v0[1],v0[2],v0[3]);
            *(int2*)(vT  + (size_t)(16+lm)*ST_N + n0) = pk4(v1[0],v1[1],v1[2],v1[3]);
        }
    }
    __syncthreads();
    // ---- phase 2: kvT[d][f] = sum_n kfT[f][n]*vT[d][n]; ksum via ones-frag ----
    {
        f32x4 acc0=(f32x4){0,0,0,0}, acc1=(f32x4){0,0,0,0}, acc2=(f32x4){0,0,0,0};
        __builtin_amdgcn_s_setprio(1);
        #pragma unroll
        for(int ks=0; ks<8; ++ks){
            bh8 aa = ld_frag(kfT + (size_t)(wv*16+lm)*ST_N + ks*32 + quad*8);
            bh8 b0 = ld_frag(vT + (size_t)lm*ST_N      + ks*32 + quad*8);
            bh8 b1 = ld_frag(vT + (size_t)(16+lm)*ST_N + ks*32 + quad*8);
            acc0 = MFMA(aa, b0, acc0, 0,0,0);
            acc1 = MFMA(aa, b1, acc1, 0,0,0);
            acc2 = MFMA(aa, onesf, acc2, 0,0,0);
        }
        __builtin_amdgcn_s_setprio(0);
        int f0 = wv*16 + quad*4;
        *(int2*)(kvT + (size_t)(lm   )*ST_F + f0) = pk4(acc0[0],acc0[1],acc0[2],acc0[3]);
        *(int2*)(kvT + (size_t)(16+lm)*ST_F + f0) = pk4(acc1[0],acc1[1],acc1[2],acc1[3]);
        if(lm==0)
            *(int2*)(kvT + (size_t)32*ST_F + f0) = pk4(acc2[0],acc2[1],acc2[2],acc2[3]);
    }
    __syncthreads();
    // ---- phase 3: qf[n][f] = featmap(zn·Wc_q^T + bc_q)  (aliases kfT/vT) ----
    {
        f32x4 acc[4][2];
        #pragma unroll
        for(int mt=0;mt<4;++mt){ acc[mt][0]=(f32x4){0,0,0,0}; acc[mt][1]=(f32x4){0,0,0,0}; }
        __builtin_amdgcn_s_setprio(1);
        #pragma unroll
        for(int ks=0; ks<4; ++ks){
            bh8 b0 = ld_frag(pb + P_CQW + h*4096 + lm*128      + ks*32 + quad*8);
            bh8 b1 = ld_frag(pb + P_CQW + h*4096 + (16+lm)*128 + ks*32 + quad*8);
            #pragma unroll
            for(int mt=0; mt<4; ++mt){
                acc[mt][0] = MFMA(a[mt][ks], b0, acc[mt][0], 0,0,0);
                acc[mt][1] = MFMA(a[mt][ks], b1, acc[mt][1], 0,0,0);
            }
        }
        __builtin_amdgcn_s_setprio(0);
        float bb0 = bf2f(pb[P_CQB + h*32 + lm]);
        float bb1 = bf2f(pb[P_CQB + h*32 + 16 + lm]);
        #pragma unroll
        for(int mt=0; mt<4; ++mt)
            #pragma unroll
            for(int r=0; r<4; ++r){
                int n = wv*64 + mt*16 + quad*4 + r;
                float m0 = fminf(8.f, fmaxf(-8.f, acc[mt][0][r] + bb0));
                float m1 = fminf(8.f, fmaxf(-8.f, acc[mt][1][r] + bb1));
                u32 q0 = pk2h(__expf( m0), __expf(-m0));
                u32 q1 = pk2h(__expf( m1), __expf(-m1));
                qf[n*ST_F + lm     ] = (u16)q0;
                qf[n*ST_F + lm + 32] = (u16)(q0>>16);
                qf[n*ST_F + lm + 16] = (u16)q1;
                qf[n*ST_F + lm + 48] = (u16)(q1>>16);
            }
    }
    __syncthreads();
    // ---- phase 4: out = (qf·kvT^T)/den * gate ----
    {
        f32x4 acc[4][3];
        #pragma unroll
        for(int mt=0;mt<4;++mt)
            #pragma unroll
            for(int nt=0;nt<3;++nt) acc[mt][nt]=(f32x4){0,0,0,0};
        __builtin_amdgcn_s_setprio(1);
        #pragma unroll
        for(int ks=0; ks<2; ++ks){
            bh8 b0 = ld_frag(kvT + (size_t)lm*ST_F      + ks*32 + quad*8);
            bh8 b1 = ld_frag(kvT + (size_t)(16+lm)*ST_F + ks*32 + quad*8);
            bh8 b2 = ld_frag(kvT + (size_t)32*ST_F      + ks*32 + quad*8); // ksum, broadcast
            #pragma unroll
            for(int mt=0; mt<4; ++mt){
                bh8 aa = ld_frag(qf + (size_t)(wv*64+mt*16+lm)*ST_F + ks*32 + quad*8);
                acc[mt][0] = MFMA(aa, b0, acc[mt][0], 0,0,0);
                acc[mt][1] = MFMA(aa, b1, acc[mt][1], 0,0,0);
                acc[mt][2] = MFMA(aa, b2, acc[mt][2], 0,0,0);
            }
        }
        __builtin_amdgcn_s_setprio(0);
        #pragma unroll
        for(int mt=0; mt<4; ++mt)
            #pragma unroll
            for(int r=0; r<4; ++r){
                int n = wv*64 + mt*16 + quad*4 + r;
                float rcp = 1.f / fmaxf(acc[mt][2][r], 1e-6f);
                u16* op = attn + ((size_t)row*256 + n)*128 + h*32;
                u32 o = pk2h(acc[mt][0][r]*rcp*gacc[mt][0][r],
                             acc[mt][1][r]*rcp*gacc[mt][1][r]);
                op[lm]    = (u16)o;
                op[16+lm] = (u16)(o>>16);
            }
    }
}

// ---------------- MFMA o-proj: attn(bf16) -> out(f32), x mask — direct f32 stores ----------------
__global__ __launch_bounds__(256,2)
void oproj_kernel(const u16* __restrict__ attn, const u16* __restrict__ pb,
                  const int* __restrict__ mask, float* __restrict__ out){
    int tid = threadIdx.x;
    int lane = tid&63, wv = tid>>6;
    int mhalf = (wv>>1)*64, nhalf = (wv&1)*64;
    int lm = lane&15, quad = lane>>4;
    int m0 = blockIdx.x*128;

    f32x4 acc[4][4];
    #pragma unroll
    for(int mt=0;mt<4;++mt)
        #pragma unroll
        for(int nt=0;nt<4;++nt)
            acc[mt][nt] = (f32x4){0.f,0.f,0.f,0.f};

    const u16* Abase = attn + (size_t)(m0 + mhalf + lm)*128 + quad*8;
    const u16* W = pb + P_OW;
    #pragma unroll
    for(int ks=0; ks<4; ++ks){
        bh8 a[4], b[4];
        #pragma unroll
        for(int mt=0; mt<4; ++mt)
            a[mt] = ld_frag(Abase + (size_t)mt*16*128 + ks*32);
        #pragma unroll
        for(int nt=0; nt<4; ++nt)
            b[nt] = ld_frag(W + (size_t)(nhalf + nt*16 + lm)*128 + ks*32 + quad*8);
        #pragma unroll
        for(int mt=0; mt<4; ++mt)
            #pragma unroll
            for(int nt=0; nt<4; ++nt)
                acc[mt][nt] = MFMA(a[mt], b[nt], acc[mt][nt], 0, 0, 0);
    }
    float bv[4];
    #pragma unroll
    for(int nt=0; nt<4; ++nt) bv[nt] = bf2f(pb[P_OB + nhalf + nt*16 + lm]);
    #pragma unroll
    for(int mt=0; mt<4; ++mt){
        int mrow = m0 + mhalf + mt*16 + quad*4;
        float mk[4];
        #pragma unroll
        for(int r=0;r<4;++r) mk[r] = (float)mask[mrow+r];
        #pragma unroll
        for(int r=0; r<4; ++r){
            float* orow = out + (size_t)(mrow + r)*128 + nhalf + lm;
            #pragma unroll
            for(int nt=0; nt<4; ++nt)
                orow[nt*16] = (acc[mt][nt][r] + bv[nt]) * mk[r];
        }
    }
}

// ---------------- launch: 3 kernels (prep+ln merged; mega/oproj per ledger) ----------------
extern "C" void kernel_launch(void* const* d_in, const int* in_sizes, int n_in,
                              void* d_out, int out_size, void* d_ws, size_t ws_size,
                              hipStream_t stream){
    const float* z    = (const float*)d_in[0];
    const int*   mask = (const int*)d_in[1];

    char* ws = (char*)d_ws;
    const size_t MB = (size_t)1<<20;
    u16* zn   = (u16*)(ws + 0*MB);      // 16 MB [t][128] bf16
    u16* attn = (u16*)(ws + 16*MB);     // 16 MB [t][128] bf16
    u16* pb   = (u16*)(ws + 32*MB);     // ~231 KB bf16 param block

    prep_ln_kernel<<<NCONV+129+LN_BLOCKS,256,0,stream>>>(
        (const float*)d_in[2],  (const float*)d_in[3],  (const float*)d_in[4],  (const float*)d_in[5],
        (const float*)d_in[6],  (const float*)d_in[7],  (const float*)d_in[8],  (const float*)d_in[9],
        (const float*)d_in[10], (const float*)d_in[11], (const float*)d_in[12], (const float*)d_in[13],
        (const float*)d_in[14], (const float*)d_in[15], (const float*)d_in[16], (const float*)d_in[17],
        pb, z, zn);
    mega_kernel<<<1024,256,0,stream>>>(zn, mask, pb, attn);
    oproj_kernel<<<512,256,0,stream>>>(attn, pb, mask, (float*)d_out);
}

// Round 14
// 172.906 us; speedup vs baseline: 1.0182x; 1.0182x over previous
//
#include <hip/hip_runtime.h>
#include <hip/hip_bf16.h>
#include <stdint.h>

#define DEV __device__ __forceinline__

typedef unsigned short u16;
typedef unsigned int u32;
typedef short bh8 __attribute__((ext_vector_type(8)));
typedef float f32x4 __attribute__((ext_vector_type(4)));

// ---------- bf16 helpers ----------
DEV float bf2f(u16 v){ return __uint_as_float(((u32)v)<<16); }
DEV u16 f2bf(float f){
    u32 x = __float_as_uint(f);
    x += 0x7fffu + ((x>>16)&1u);
    return (u16)(x>>16);
}
// Hot-path conversions via hip_bf16 API (RNE, same rounding as f2bf; compiler
// lowers to v_cvt_pk_bf16_f32 — R13 verified: VALUBusy 32->28, no spill).
DEV u32 pk2h(float a, float b){
    float2 t; t.x = a; t.y = b;
    __hip_bfloat162 h = __float22bfloat162_rn(t);
    union{ __hip_bfloat162 h; u32 u; } c; c.h = h; return c.u;
}
DEV int2 pk4(float a, float b, float c, float d){
    int2 r;
    r.x = (int)pk2h(a, b);
    r.y = (int)pk2h(c, d);
    return r;
}
DEV bh8 ld_frag(const u16* p){
    int4 v = *(const int4*)p;
    union{ int4 i; bh8 h; } u; u.i = v; return u.h;
}
#define MFMA __builtin_amdgcn_mfma_f32_16x16x32_bf16

// Problem constants: BSZ=1, S=256, C=128, H=4, D=32, F=64. f32 I/O, bf16 internal.
//
// Session ledger:
//  R0: 4 kernels, mega 46.0, total 182.7
//  R1-R3,R11: occupancy chase (3/CU, 512-thr@40% occ): ALL slower. mega is
//      serial-chain/latency-bound, not wave-count-bound.
//  R4: hand-written asm cvt_pk -> NaN. FAILED (API casts fine, R13).
//  R5/R6/R7/R9/R10: five LN-fusion variants failed. ln stays separate.
//  R8: prep if-chain + oproj direct-store: mega 45.1, total 175.8
//  R12: prep+ln merged, ln grid-strided: total 174.4. Launch overhead ~1-5us.
//  R13: cvt_pk epilogues + setprio: VALUBusy 32->28, mega time UNCHANGED 45.
//      => VALU not critical path either.
//  R14 (this): SINGLE variable vs R13 — XCD swizzle on mega block mapping.
//      4 head-blocks of a row currently land on 4 XCDs => zn row fetched 4x
//      (FETCH 33.6MB ~= 2x unique). Swizzle u=(g&7)*128+(g>>3) co-locates them
//      (mechanism verified R5/R6/R10: FETCH 21.5-26MB, but time was spill-
//      confounded there; this is the clean A/B). Predict FETCH -> 15-20MB;
//      mega 41-45. If FETCH drops & time doesn't: mega = structural plateau.

// Param block layout (elements, bf16) inside workspace:
#define P_LNW 0
#define P_LNB 128
#define P_QW  256
#define P_QB  16640
#define P_KW  16768
#define P_KB  33152
#define P_VW  33280
#define P_VB  49664
#define P_QFW 49792
#define P_QFB 50816
#define P_KFW 50848
#define P_KFB 51872
#define P_GW  51904
#define P_GB  68288
#define P_OW  68416
#define P_OB  84800
#define P_TOT 84928
#define P_CQW 84928    // [h][j][c] 4*32*128
#define P_CQB 101312   // [h][j]    4*32
#define P_CKW 101440
#define P_CKB 117824

#define NCONV 332
#define LN_BLOCKS 2048     // 2048 blocks x 32 tokens = 65536 tokens

// ---------------- prep + LN merged (independent work, one launch) ----------------
__global__ void prep_ln_kernel(
    const float* p0, const float* p1, const float* p2, const float* p3,
    const float* p4, const float* p5, const float* p6, const float* p7,
    const float* p8, const float* p9, const float* p10, const float* p11,
    const float* p12, const float* p13, const float* p14, const float* p15,
    u16* __restrict__ dst,
    const float* __restrict__ z, u16* __restrict__ zn){
    int b = blockIdx.x, tid = threadIdx.x;
    if(b < NCONV){
        int idx = b*256 + tid;
        if(idx >= P_TOT) return;
        // if-chain (cndmask), NOT runtime-indexed local arrays (rule #20 -> scratch).
        const float* sp = p0; int base = P_LNW;
        if(idx >= P_LNB){ sp = p1;  base = P_LNB; }
        if(idx >= P_QW ){ sp = p2;  base = P_QW;  }
        if(idx >= P_QB ){ sp = p3;  base = P_QB;  }
        if(idx >= P_KW ){ sp = p4;  base = P_KW;  }
        if(idx >= P_KB ){ sp = p5;  base = P_KB;  }
        if(idx >= P_VW ){ sp = p6;  base = P_VW;  }
        if(idx >= P_VB ){ sp = p7;  base = P_VB;  }
        if(idx >= P_QFW){ sp = p8;  base = P_QFW; }
        if(idx >= P_QFB){ sp = p9;  base = P_QFB; }
        if(idx >= P_KFW){ sp = p10; base = P_KFW; }
        if(idx >= P_KFB){ sp = p11; base = P_KFB; }
        if(idx >= P_GW ){ sp = p12; base = P_GW;  }
        if(idx >= P_GB ){ sp = p13; base = P_GB;  }
        if(idx >= P_OW ){ sp = p14; base = P_OW;  }
        if(idx >= P_OB ){ sp = p15; base = P_OB;  }
        dst[idx] = f2bf(sp[idx - base]);
    } else if(b < NCONV + 128){
        // combined weights: Wc[h][j][c] = sum_d F[j][d] * W[h*32+d][c]
        int idx = (b - NCONV)*256 + tid;            // [0, 32768)
        int sel = idx >> 14;
        int rem = idx & 16383;
        int h = rem >> 12, j = (rem >> 7) & 31, c = rem & 127;
        const float* FWp = sel ? p10 : p8;
        const float* Wp  = sel ? p4  : p2;
        float s = 0.f;
        #pragma unroll
        for(int d=0; d<32; ++d)
            s += FWp[j*32+d] * Wp[(h*32+d)*128 + c];
        dst[(sel ? P_CKW : P_CQW) + h*4096 + j*128 + c] = f2bf(s);
    } else if(b == NCONV + 128){
        // combined biases: bc[h][j] = sum_d F[j][d]*b[h*32+d] + fb[j]
        int t = tid;
        int sel = t >> 7, h = (t >> 5) & 3, j = t & 31;
        const float* FWp = sel ? p10 : p8;
        const float* FBp = sel ? p11 : p9;
        const float* Bp  = sel ? p5  : p3;
        float s = FBp[j];
        #pragma unroll
        for(int d=0; d<32; ++d)
            s += FWp[j*32+d] * Bp[h*32+d];
        dst[(sel ? P_CKB : P_CQB) + h*32 + j] = f2bf(s);
    } else {
        // ---- LayerNorm, grid-strided: 32 tokens/block, 8 per wave ----
        int lb = b - (NCONV + 129);                 // [0, LN_BLOCKS)
        int lane = tid & 63, wv = tid >> 6;
        int c0 = 2*lane;
        float w0 = p0[c0], w1 = p0[c0+1];
        float b0 = p1[c0], b1 = p1[c0+1];
        #pragma unroll 1
        for(int it=0; it<8; ++it){
            int t = lb*32 + it*4 + wv;
            float2 v = ((const float2*)z)[(size_t)t*64 + lane];
            float x0 = v.x, x1 = v.y;
            float s = x0 + x1, s2 = x0*x0 + x1*x1;
            #pragma unroll
            for(int o=1;o<64;o<<=1){ s += __shfl_xor(s,o,64); s2 += __shfl_xor(s2,o,64); }
            float mean = s*(1.f/128.f);
            float var  = s2*(1.f/128.f) - mean*mean;
            float rs = rsqrtf(var + 1e-5f);
            float o0 = (x0-mean)*rs*w0 + b0;
            float o1 = (x1-mean)*rs*w1 + b1;
            u32 po = (u32)f2bf(o0) | ((u32)f2bf(o1)<<16);
            *(u32*)(zn + (size_t)t*128 + c0) = po;
        }
    }
}

// ---------------- mega kernel: one block per (row, head), XCD-swizzled ----------------
// LDS (bytes):
//   mask_f [256 f32]      @ 0       (1024)
//   kfT    [64][264] u16  @ 1024    (33792)  kf^T [f][n], masked
//   vT     [32][264] u16  @ 34816   (16896)  v^T [d][n] masked
//   qf     [256][68] u16  @ 1024    (34816)  aliases kfT(+vT head); [n][f]
//   kvT    [33][68]  u16  @ 51712   (4488)   kv^T [d][f]; row 32 = ksum
#define ST_N 264
#define ST_F 68
#define SM_KF   1024
#define SM_VT   34816
#define SM_QF   1024
#define SM_KVT  51712
#define SM_TOT  56200

__global__ __launch_bounds__(256,2)
void mega_kernel(const u16* __restrict__ zn, const int* __restrict__ mask,
                 const u16* __restrict__ pb, u16* __restrict__ attn){
    __shared__ __align__(16) char smem[SM_TOT];
    float* mask_f = (float*)smem;
    u16* kfT = (u16*)(smem + SM_KF);
    u16* vT  = (u16*)(smem + SM_VT);
    u16* qf  = (u16*)(smem + SM_QF);
    u16* kvT = (u16*)(smem + SM_KVT);

    // R14: XCD swizzle (bijective on [0,1024), 1024%8==0). Blocks dispatch
    // round-robin to XCDs by blockIdx; this mapping puts the 4 head-blocks of
    // each row on ONE XCD so its 64KB zn row is fetched into one L2, not four.
    int g = blockIdx.x;
    int u = (g & 7)*128 + (g >> 3);
    int row = u >> 2, h = u & 3;
    int tid = threadIdx.x, lane = tid & 63, wv = tid >> 6;
    int lm = lane & 15, quad = lane >> 4;

    mask_f[tid] = (float)mask[row*256 + tid];

    // zn A-frags: loaded once, reused by all GEMM phases
    bh8 a[4][4];
    {
        const u16* Ab = zn + ((size_t)row*256 + wv*64 + lm)*128 + quad*8;
        #pragma unroll
        for(int mt=0; mt<4; ++mt)
            #pragma unroll
            for(int ks=0; ks<4; ++ks)
                a[mt][ks] = ld_frag(Ab + (size_t)mt*16*128 + ks*32);
    }
    bh8 onesf;
    { union{int4 i; bh8 h;} uo; uo.i.x=uo.i.y=uo.i.z=uo.i.w=0x3F803F80; onesf = uo.h; }

    __syncthreads();

    f32x4 gacc[4][2];
    // ---- phase 1 (merged): B = [ck0 ck1 | v0 v1 | g0 g1], shared A ----
    {
        f32x4 acc[4][6];
        #pragma unroll
        for(int mt=0;mt<4;++mt)
            #pragma unroll
            for(int j=0;j<6;++j) acc[mt][j] = (f32x4){0,0,0,0};
        __builtin_amdgcn_s_setprio(1);
        #pragma unroll
        for(int ks=0; ks<4; ++ks){
            bh8 b[6];
            b[0] = ld_frag(pb + P_CKW + h*4096 + lm*128            + ks*32 + quad*8);
            b[1] = ld_frag(pb + P_CKW + h*4096 + (16+lm)*128       + ks*32 + quad*8);
            b[2] = ld_frag(pb + P_VW + (size_t)(h*32 + lm)*128     + ks*32 + quad*8);
            b[3] = ld_frag(pb + P_VW + (size_t)(h*32 + 16+lm)*128  + ks*32 + quad*8);
            b[4] = ld_frag(pb + P_GW + (size_t)(h*32 + lm)*128     + ks*32 + quad*8);
            b[5] = ld_frag(pb + P_GW + (size_t)(h*32 + 16+lm)*128  + ks*32 + quad*8);
            #pragma unroll
            for(int mt=0; mt<4; ++mt)
                #pragma unroll
                for(int j=0;j<6;++j)
                    acc[mt][j] = MFMA(a[mt][ks], b[j], acc[mt][j], 0,0,0);
        }
        __builtin_amdgcn_s_setprio(0);
        float bk0 = bf2f(pb[P_CKB + h*32 + lm]);
        float bk1 = bf2f(pb[P_CKB + h*32 + 16 + lm]);
        float bv0 = bf2f(pb[P_VB + h*32 + lm]);
        float bv1 = bf2f(pb[P_VB + h*32 + 16 + lm]);
        float bg0 = bf2f(pb[P_GB + h*32 + lm]);
        float bg1 = bf2f(pb[P_GB + h*32 + 16 + lm]);
        #pragma unroll
        for(int mt=0; mt<4; ++mt){
            int n0 = wv*64 + mt*16 + quad*4;
            float ep0[4], em0[4], ep1[4], em1[4], v0[4], v1[4];
            #pragma unroll
            for(int r=0; r<4; ++r){
                float mk = mask_f[n0+r];
                float m0 = fminf(8.f, fmaxf(-8.f, acc[mt][0][r] + bk0));
                float m1 = fminf(8.f, fmaxf(-8.f, acc[mt][1][r] + bk1));
                ep0[r] = __expf( m0)*mk;  em0[r] = __expf(-m0)*mk;
                ep1[r] = __expf( m1)*mk;  em1[r] = __expf(-m1)*mk;
                v0[r] = (acc[mt][2][r] + bv0)*mk;
                v1[r] = (acc[mt][3][r] + bv1)*mk;
                gacc[mt][0][r] = 1.f/(1.f + __expf(-(acc[mt][4][r] + bg0)));
                gacc[mt][1][r] = 1.f/(1.f + __expf(-(acc[mt][5][r] + bg1)));
            }
            *(int2*)(kfT + (size_t)(lm   )*ST_N + n0) = pk4(ep0[0],ep0[1],ep0[2],ep0[3]);
            *(int2*)(kfT + (size_t)(lm+32)*ST_N + n0) = pk4(em0[0],em0[1],em0[2],em0[3]);
            *(int2*)(kfT + (size_t)(lm+16)*ST_N + n0) = pk4(ep1[0],ep1[1],ep1[2],ep1[3]);
            *(int2*)(kfT + (size_t)(lm+48)*ST_N + n0) = pk4(em1[0],em1[1],em1[2],em1[3]);
            *(int2*)(vT  + (size_t)(lm   )*ST_N + n0) = pk4(v0[0],v0[1],v0[2],v0[3]);
            *(int2*)(vT  + (size_t)(16+lm)*ST_N + n0) = pk4(v1[0],v1[1],v1[2],v1[3]);
        }
    }
    __syncthreads();
    // ---- phase 2: kvT[d][f] = sum_n kfT[f][n]*vT[d][n]; ksum via ones-frag ----
    {
        f32x4 acc0=(f32x4){0,0,0,0}, acc1=(f32x4){0,0,0,0}, acc2=(f32x4){0,0,0,0};
        __builtin_amdgcn_s_setprio(1);
        #pragma unroll
        for(int ks=0; ks<8; ++ks){
            bh8 aa = ld_frag(kfT + (size_t)(wv*16+lm)*ST_N + ks*32 + quad*8);
            bh8 b0 = ld_frag(vT + (size_t)lm*ST_N      + ks*32 + quad*8);
            bh8 b1 = ld_frag(vT + (size_t)(16+lm)*ST_N + ks*32 + quad*8);
            acc0 = MFMA(aa, b0, acc0, 0,0,0);
            acc1 = MFMA(aa, b1, acc1, 0,0,0);
            acc2 = MFMA(aa, onesf, acc2, 0,0,0);
        }
        __builtin_amdgcn_s_setprio(0);
        int f0 = wv*16 + quad*4;
        *(int2*)(kvT + (size_t)(lm   )*ST_F + f0) = pk4(acc0[0],acc0[1],acc0[2],acc0[3]);
        *(int2*)(kvT + (size_t)(16+lm)*ST_F + f0) = pk4(acc1[0],acc1[1],acc1[2],acc1[3]);
        if(lm==0)
            *(int2*)(kvT + (size_t)32*ST_F + f0) = pk4(acc2[0],acc2[1],acc2[2],acc2[3]);
    }
    __syncthreads();
    // ---- phase 3: qf[n][f] = featmap(zn·Wc_q^T + bc_q)  (aliases kfT/vT) ----
    {
        f32x4 acc[4][2];
        #pragma unroll
        for(int mt=0;mt<4;++mt){ acc[mt][0]=(f32x4){0,0,0,0}; acc[mt][1]=(f32x4){0,0,0,0}; }
        __builtin_amdgcn_s_setprio(1);
        #pragma unroll
        for(int ks=0; ks<4; ++ks){
            bh8 b0 = ld_frag(pb + P_CQW + h*4096 + lm*128      + ks*32 + quad*8);
            bh8 b1 = ld_frag(pb + P_CQW + h*4096 + (16+lm)*128 + ks*32 + quad*8);
            #pragma unroll
            for(int mt=0; mt<4; ++mt){
                acc[mt][0] = MFMA(a[mt][ks], b0, acc[mt][0], 0,0,0);
                acc[mt][1] = MFMA(a[mt][ks], b1, acc[mt][1], 0,0,0);
            }
        }
        __builtin_amdgcn_s_setprio(0);
        float bb0 = bf2f(pb[P_CQB + h*32 + lm]);
        float bb1 = bf2f(pb[P_CQB + h*32 + 16 + lm]);
        #pragma unroll
        for(int mt=0; mt<4; ++mt)
            #pragma unroll
            for(int r=0; r<4; ++r){
                int n = wv*64 + mt*16 + quad*4 + r;
                float m0 = fminf(8.f, fmaxf(-8.f, acc[mt][0][r] + bb0));
                float m1 = fminf(8.f, fmaxf(-8.f, acc[mt][1][r] + bb1));
                u32 q0 = pk2h(__expf( m0), __expf(-m0));
                u32 q1 = pk2h(__expf( m1), __expf(-m1));
                qf[n*ST_F + lm     ] = (u16)q0;
                qf[n*ST_F + lm + 32] = (u16)(q0>>16);
                qf[n*ST_F + lm + 16] = (u16)q1;
                qf[n*ST_F + lm + 48] = (u16)(q1>>16);
            }
    }
    __syncthreads();
    // ---- phase 4: out = (qf·kvT^T)/den * gate ----
    {
        f32x4 acc[4][3];
        #pragma unroll
        for(int mt=0;mt<4;++mt)
            #pragma unroll
            for(int nt=0;nt<3;++nt) acc[mt][nt]=(f32x4){0,0,0,0};
        __builtin_amdgcn_s_setprio(1);
        #pragma unroll
        for(int ks=0; ks<2; ++ks){
            bh8 b0 = ld_frag(kvT + (size_t)lm*ST_F      + ks*32 + quad*8);
            bh8 b1 = ld_frag(kvT + (size_t)(16+lm)*ST_F + ks*32 + quad*8);
            bh8 b2 = ld_frag(kvT + (size_t)32*ST_F      + ks*32 + quad*8); // ksum, broadcast
            #pragma unroll
            for(int mt=0; mt<4; ++mt){
                bh8 aa = ld_frag(qf + (size_t)(wv*64+mt*16+lm)*ST_F + ks*32 + quad*8);
                acc[mt][0] = MFMA(aa, b0, acc[mt][0], 0,0,0);
                acc[mt][1] = MFMA(aa, b1, acc[mt][1], 0,0,0);
                acc[mt][2] = MFMA(aa, b2, acc[mt][2], 0,0,0);
            }
        }
        __builtin_amdgcn_s_setprio(0);
        #pragma unroll
        for(int mt=0; mt<4; ++mt)
            #pragma unroll
            for(int r=0; r<4; ++r){
                int n = wv*64 + mt*16 + quad*4 + r;
                float rcp = 1.f / fmaxf(acc[mt][2][r], 1e-6f);
                u16* op = attn + ((size_t)row*256 + n)*128 + h*32;
                u32 o = pk2h(acc[mt][0][r]*rcp*gacc[mt][0][r],
                             acc[mt][1][r]*rcp*gacc[mt][1][r]);
                op[lm]    = (u16)o;
                op[16+lm] = (u16)(o>>16);
            }
    }
}

// ---------------- MFMA o-proj: attn(bf16) -> out(f32), x mask — direct f32 stores ----------------
__global__ __launch_bounds__(256,2)
void oproj_kernel(const u16* __restrict__ attn, const u16* __restrict__ pb,
                  const int* __restrict__ mask, float* __restrict__ out){
    int tid = threadIdx.x;
    int lane = tid&63, wv = tid>>6;
    int mhalf = (wv>>1)*64, nhalf = (wv&1)*64;
    int lm = lane&15, quad = lane>>4;
    int m0 = blockIdx.x*128;

    f32x4 acc[4][4];
    #pragma unroll
    for(int mt=0;mt<4;++mt)
        #pragma unroll
        for(int nt=0;nt<4;++nt)
            acc[mt][nt] = (f32x4){0.f,0.f,0.f,0.f};

    const u16* Abase = attn + (size_t)(m0 + mhalf + lm)*128 + quad*8;
    const u16* W = pb + P_OW;
    #pragma unroll
    for(int ks=0; ks<4; ++ks){
        bh8 a[4], b[4];
        #pragma unroll
        for(int mt=0; mt<4; ++mt)
            a[mt] = ld_frag(Abase + (size_t)mt*16*128 + ks*32);
        #pragma unroll
        for(int nt=0; nt<4; ++nt)
            b[nt] = ld_frag(W + (size_t)(nhalf + nt*16 + lm)*128 + ks*32 + quad*8);
        #pragma unroll
        for(int mt=0; mt<4; ++mt)
            #pragma unroll
            for(int nt=0; nt<4; ++nt)
                acc[mt][nt] = MFMA(a[mt], b[nt], acc[mt][nt], 0, 0, 0);
    }
    float bv[4];
    #pragma unroll
    for(int nt=0; nt<4; ++nt) bv[nt] = bf2f(pb[P_OB + nhalf + nt*16 + lm]);
    #pragma unroll
    for(int mt=0; mt<4; ++mt){
        int mrow = m0 + mhalf + mt*16 + quad*4;
        float mk[4];
        #pragma unroll
        for(int r=0;r<4;++r) mk[r] = (float)mask[mrow+r];
        #pragma unroll
        for(int r=0; r<4; ++r){
            float* orow = out + (size_t)(mrow + r)*128 + nhalf + lm;
            #pragma unroll
            for(int nt=0; nt<4; ++nt)
                orow[nt*16] = (acc[mt][nt][r] + bv[nt]) * mk[r];
        }
    }
}

// ---------------- launch: 3 kernels (prep+ln merged; mega XCD-swizzled) ----------------
extern "C" void kernel_launch(void* const* d_in, const int* in_sizes, int n_in,
                              void* d_out, int out_size, void* d_ws, size_t ws_size,
                              hipStream_t stream){
    const float* z    = (const float*)d_in[0];
    const int*   mask = (const int*)d_in[1];

    char* ws = (char*)d_ws;
    const size_t MB = (size_t)1<<20;
    u16* zn   = (u16*)(ws + 0*MB);      // 16 MB [t][128] bf16
    u16* attn = (u16*)(ws + 16*MB);     // 16 MB [t][128] bf16
    u16* pb   = (u16*)(ws + 32*MB);     // ~231 KB bf16 param block

    prep_ln_kernel<<<NCONV+129+LN_BLOCKS,256,0,stream>>>(
        (const float*)d_in[2],  (const float*)d_in[3],  (const float*)d_in[4],  (const float*)d_in[5],
        (const float*)d_in[6],  (const float*)d_in[7],  (const float*)d_in[8],  (const float*)d_in[9],
        (const float*)d_in[10], (const float*)d_in[11], (const float*)d_in[12], (const float*)d_in[13],
        (const float*)d_in[14], (const float*)d_in[15], (const float*)d_in[16], (const float*)d_in[17],
        pb, z, zn);
    mega_kernel<<<1024,256,0,stream>>>(zn, mask, pb, attn);
    oproj_kernel<<<512,256,0,stream>>>(attn, pb, mask, (float*)d_out);
}

// Round 15
// 171.822 us; speedup vs baseline: 1.0246x; 1.0063x over previous
//
#include <hip/hip_runtime.h>
#include <hip/hip_bf16.h>
#include <stdint.h>

#define DEV __device__ __forceinline__

typedef unsigned short u16;
typedef unsigned int u32;
typedef short bh8 __attribute__((ext_vector_type(8)));
typedef float f32x4 __attribute__((ext_vector_type(4)));

// ---------- bf16 helpers ----------
DEV float bf2f(u16 v){ return __uint_as_float(((u32)v)<<16); }
DEV u16 f2bf(float f){
    u32 x = __float_as_uint(f);
    x += 0x7fffu + ((x>>16)&1u);
    return (u16)(x>>16);
}
// Hot-path conversions via hip_bf16 API (RNE, same rounding as f2bf; compiler
// lowers to v_cvt_pk_bf16_f32 — R13 verified: VALUBusy 32->28, no spill).
DEV u32 pk2h(float a, float b){
    float2 t; t.x = a; t.y = b;
    __hip_bfloat162 h = __float22bfloat162_rn(t);
    union{ __hip_bfloat162 h; u32 u; } c; c.h = h; return c.u;
}
DEV int2 pk4(float a, float b, float c, float d){
    int2 r;
    r.x = (int)pk2h(a, b);
    r.y = (int)pk2h(c, d);
    return r;
}
DEV bh8 ld_frag(const u16* p){
    int4 v = *(const int4*)p;
    union{ int4 i; bh8 h; } u; u.i = v; return u.h;
}
#define MFMA __builtin_amdgcn_mfma_f32_16x16x32_bf16

// Problem constants: BSZ=1, S=256, C=128, H=4, D=32, F=64. f32 I/O, bf16 internal.
//
// Session ledger:
//  R0: 4 kernels, mega 46.0, total 182.7
//  R1-R3,R11: occupancy chase: ALL slower. Not wave-count-bound.
//  R4: hand-written asm cvt_pk -> NaN. FAILED (API casts fine, R13).
//  R5/R6/R7/R9/R10: five LN-fusion variants failed. ln stays separate.
//  R8: prep if-chain + oproj direct-store: mega 45.1, total 175.8
//  R12: prep+ln merged, ln grid-strided: total 174.4. Launch overhead ~1-5us.
//  R13: cvt_pk epilogues + setprio: VALUBusy 32->28, time UNCHANGED. Not VALU-bound.
//  R14: XCD swizzle: FETCH 33.6->9.0MB (!), time UNCHANGED 44.5. Not fetch-bound.
//      total 172.9 (best). => mega = per-block serial latency chain.
//  R15 (this): shorten the chain — phase-3 GEMM folded into phase 1 (same A,
//      independent B: 6->8 B-columns, 128 MFMAs in one stage); phase 3 becomes a
//      pure epilogue (bias+exp+qf stores after phase-2 barrier, since qf aliases
//      kfT/vT). a[] live range shrinks to phase 1. +32 AGPR accs held across
//      phase 2. Spill detector: WRITE_SIZE must stay 16384.
//      Freebie (different kernel): LN token loop un-serialized (drop unroll 1).

// Param block layout (elements, bf16) inside workspace:
#define P_LNW 0
#define P_LNB 128
#define P_QW  256
#define P_QB  16640
#define P_KW  16768
#define P_KB  33152
#define P_VW  33280
#define P_VB  49664
#define P_QFW 49792
#define P_QFB 50816
#define P_KFW 50848
#define P_KFB 51872
#define P_GW  51904
#define P_GB  68288
#define P_OW  68416
#define P_OB  84800
#define P_TOT 84928
#define P_CQW 84928    // [h][j][c] 4*32*128
#define P_CQB 101312   // [h][j]    4*32
#define P_CKW 101440
#define P_CKB 117824

#define NCONV 332
#define LN_BLOCKS 2048     // 2048 blocks x 32 tokens = 65536 tokens

// ---------------- prep + LN merged (independent work, one launch) ----------------
__global__ void prep_ln_kernel(
    const float* p0, const float* p1, const float* p2, const float* p3,
    const float* p4, const float* p5, const float* p6, const float* p7,
    const float* p8, const float* p9, const float* p10, const float* p11,
    const float* p12, const float* p13, const float* p14, const float* p15,
    u16* __restrict__ dst,
    const float* __restrict__ z, u16* __restrict__ zn){
    int b = blockIdx.x, tid = threadIdx.x;
    if(b < NCONV){
        int idx = b*256 + tid;
        if(idx >= P_TOT) return;
        // if-chain (cndmask), NOT runtime-indexed local arrays (rule #20 -> scratch).
        const float* sp = p0; int base = P_LNW;
        if(idx >= P_LNB){ sp = p1;  base = P_LNB; }
        if(idx >= P_QW ){ sp = p2;  base = P_QW;  }
        if(idx >= P_QB ){ sp = p3;  base = P_QB;  }
        if(idx >= P_KW ){ sp = p4;  base = P_KW;  }
        if(idx >= P_KB ){ sp = p5;  base = P_KB;  }
        if(idx >= P_VW ){ sp = p6;  base = P_VW;  }
        if(idx >= P_VB ){ sp = p7;  base = P_VB;  }
        if(idx >= P_QFW){ sp = p8;  base = P_QFW; }
        if(idx >= P_QFB){ sp = p9;  base = P_QFB; }
        if(idx >= P_KFW){ sp = p10; base = P_KFW; }
        if(idx >= P_KFB){ sp = p11; base = P_KFB; }
        if(idx >= P_GW ){ sp = p12; base = P_GW;  }
        if(idx >= P_GB ){ sp = p13; base = P_GB;  }
        if(idx >= P_OW ){ sp = p14; base = P_OW;  }
        if(idx >= P_OB ){ sp = p15; base = P_OB;  }
        dst[idx] = f2bf(sp[idx - base]);
    } else if(b < NCONV + 128){
        // combined weights: Wc[h][j][c] = sum_d F[j][d] * W[h*32+d][c]
        int idx = (b - NCONV)*256 + tid;            // [0, 32768)
        int sel = idx >> 14;
        int rem = idx & 16383;
        int h = rem >> 12, j = (rem >> 7) & 31, c = rem & 127;
        const float* FWp = sel ? p10 : p8;
        const float* Wp  = sel ? p4  : p2;
        float s = 0.f;
        #pragma unroll
        for(int d=0; d<32; ++d)
            s += FWp[j*32+d] * Wp[(h*32+d)*128 + c];
        dst[(sel ? P_CKW : P_CQW) + h*4096 + j*128 + c] = f2bf(s);
    } else if(b == NCONV + 128){
        // combined biases: bc[h][j] = sum_d F[j][d]*b[h*32+d] + fb[j]
        int t = tid;
        int sel = t >> 7, h = (t >> 5) & 3, j = t & 31;
        const float* FWp = sel ? p10 : p8;
        const float* FBp = sel ? p11 : p9;
        const float* Bp  = sel ? p5  : p3;
        float s = FBp[j];
        #pragma unroll
        for(int d=0; d<32; ++d)
            s += FWp[j*32+d] * Bp[h*32+d];
        dst[(sel ? P_CKB : P_CQB) + h*32 + j] = f2bf(s);
    } else {
        // ---- LayerNorm, grid-strided: 32 tokens/block, 8 per wave ----
        // R15: no unroll-1 pin — let the compiler pipeline the 8 token loads
        // (liveness here is tiny; the serial pin was a mega-context carryover).
        int lb = b - (NCONV + 129);                 // [0, LN_BLOCKS)
        int lane = tid & 63, wv = tid >> 6;
        int c0 = 2*lane;
        float w0 = p0[c0], w1 = p0[c0+1];
        float b0 = p1[c0], b1 = p1[c0+1];
        #pragma unroll
        for(int it=0; it<8; ++it){
            int t = lb*32 + it*4 + wv;
            float2 v = ((const float2*)z)[(size_t)t*64 + lane];
            float x0 = v.x, x1 = v.y;
            float s = x0 + x1, s2 = x0*x0 + x1*x1;
            #pragma unroll
            for(int o=1;o<64;o<<=1){ s += __shfl_xor(s,o,64); s2 += __shfl_xor(s2,o,64); }
            float mean = s*(1.f/128.f);
            float var  = s2*(1.f/128.f) - mean*mean;
            float rs = rsqrtf(var + 1e-5f);
            float o0 = (x0-mean)*rs*w0 + b0;
            float o1 = (x1-mean)*rs*w1 + b1;
            u32 po = (u32)f2bf(o0) | ((u32)f2bf(o1)<<16);
            *(u32*)(zn + (size_t)t*128 + c0) = po;
        }
    }
}

// ---------------- mega kernel: one block per (row, head), XCD-swizzled ----------------
// R15 structure: 3 GEMM stages instead of 4.
//   stage A (phase 1): B = [ck0 ck1 | v0 v1 | g0 g1 | cq0 cq1] — 8 cols, 128 MFMA.
//     epilogue converts cols 0..5 (kfT, vT, gacc); cq accs (cols 6,7) held in regs.
//   barrier -> phase 2 (kv GEMM) -> barrier
//   qf epilogue: bias+exp on held cq accs -> qf writes (aliases kfT/vT, now dead)
//   barrier -> phase 4 (output GEMM).
// LDS (bytes):
//   mask_f [256 f32]      @ 0       (1024)
//   kfT    [64][264] u16  @ 1024    (33792)
//   vT     [32][264] u16  @ 34816   (16896)
//   qf     [256][68] u16  @ 1024    (34816)  aliases kfT(+vT head)
//   kvT    [33][68]  u16  @ 51712   (4488)
#define ST_N 264
#define ST_F 68
#define SM_KF   1024
#define SM_VT   34816
#define SM_QF   1024
#define SM_KVT  51712
#define SM_TOT  56200

__global__ __launch_bounds__(256,2)
void mega_kernel(const u16* __restrict__ zn, const int* __restrict__ mask,
                 const u16* __restrict__ pb, u16* __restrict__ attn){
    __shared__ __align__(16) char smem[SM_TOT];
    float* mask_f = (float*)smem;
    u16* kfT = (u16*)(smem + SM_KF);
    u16* vT  = (u16*)(smem + SM_VT);
    u16* qf  = (u16*)(smem + SM_QF);
    u16* kvT = (u16*)(smem + SM_KVT);

    // XCD swizzle (R14-verified: FETCH 33.6->9.0MB). Bijective on [0,1024).
    int g = blockIdx.x;
    int u = (g & 7)*128 + (g >> 3);
    int row = u >> 2, h = u & 3;
    int tid = threadIdx.x, lane = tid & 63, wv = tid >> 6;
    int lm = lane & 15, quad = lane >> 4;

    mask_f[tid] = (float)mask[row*256 + tid];

    bh8 onesf;
    { union{int4 i; bh8 hh;} uo; uo.i.x=uo.i.y=uo.i.z=uo.i.w=0x3F803F80; onesf = uo.hh; }

    __syncthreads();

    f32x4 gacc[4][2];
    f32x4 qacc[4][2];   // cq accumulators, held across phase 2
    // ---- stage A: B = [ck0 ck1 | v0 v1 | g0 g1 | cq0 cq1], shared A (128 MFMA) ----
    {
        // zn A-frags: live only in this stage now
        bh8 a[4][4];
        {
            const u16* Ab = zn + ((size_t)row*256 + wv*64 + lm)*128 + quad*8;
            #pragma unroll
            for(int mt=0; mt<4; ++mt)
                #pragma unroll
                for(int ks=0; ks<4; ++ks)
                    a[mt][ks] = ld_frag(Ab + (size_t)mt*16*128 + ks*32);
        }
        f32x4 acc[4][6];
        #pragma unroll
        for(int mt=0;mt<4;++mt){
            #pragma unroll
            for(int j=0;j<6;++j) acc[mt][j] = (f32x4){0,0,0,0};
            qacc[mt][0] = (f32x4){0,0,0,0};
            qacc[mt][1] = (f32x4){0,0,0,0};
        }
        __builtin_amdgcn_s_setprio(1);
        #pragma unroll
        for(int ks=0; ks<4; ++ks){
            bh8 b[8];
            b[0] = ld_frag(pb + P_CKW + h*4096 + lm*128            + ks*32 + quad*8);
            b[1] = ld_frag(pb + P_CKW + h*4096 + (16+lm)*128       + ks*32 + quad*8);
            b[2] = ld_frag(pb + P_VW + (size_t)(h*32 + lm)*128     + ks*32 + quad*8);
            b[3] = ld_frag(pb + P_VW + (size_t)(h*32 + 16+lm)*128  + ks*32 + quad*8);
            b[4] = ld_frag(pb + P_GW + (size_t)(h*32 + lm)*128     + ks*32 + quad*8);
            b[5] = ld_frag(pb + P_GW + (size_t)(h*32 + 16+lm)*128  + ks*32 + quad*8);
            b[6] = ld_frag(pb + P_CQW + h*4096 + lm*128            + ks*32 + quad*8);
            b[7] = ld_frag(pb + P_CQW + h*4096 + (16+lm)*128       + ks*32 + quad*8);
            #pragma unroll
            for(int mt=0; mt<4; ++mt){
                #pragma unroll
                for(int j=0;j<6;++j)
                    acc[mt][j] = MFMA(a[mt][ks], b[j], acc[mt][j], 0,0,0);
                qacc[mt][0] = MFMA(a[mt][ks], b[6], qacc[mt][0], 0,0,0);
                qacc[mt][1] = MFMA(a[mt][ks], b[7], qacc[mt][1], 0,0,0);
            }
        }
        __builtin_amdgcn_s_setprio(0);
        float bk0 = bf2f(pb[P_CKB + h*32 + lm]);
        float bk1 = bf2f(pb[P_CKB + h*32 + 16 + lm]);
        float bv0 = bf2f(pb[P_VB + h*32 + lm]);
        float bv1 = bf2f(pb[P_VB + h*32 + 16 + lm]);
        float bg0 = bf2f(pb[P_GB + h*32 + lm]);
        float bg1 = bf2f(pb[P_GB + h*32 + 16 + lm]);
        #pragma unroll
        for(int mt=0; mt<4; ++mt){
            int n0 = wv*64 + mt*16 + quad*4;
            float ep0[4], em0[4], ep1[4], em1[4], v0[4], v1[4];
            #pragma unroll
            for(int r=0; r<4; ++r){
                float mk = mask_f[n0+r];
                float m0 = fminf(8.f, fmaxf(-8.f, acc[mt][0][r] + bk0));
                float m1 = fminf(8.f, fmaxf(-8.f, acc[mt][1][r] + bk1));
                ep0[r] = __expf( m0)*mk;  em0[r] = __expf(-m0)*mk;
                ep1[r] = __expf( m1)*mk;  em1[r] = __expf(-m1)*mk;
                v0[r] = (acc[mt][2][r] + bv0)*mk;
                v1[r] = (acc[mt][3][r] + bv1)*mk;
                gacc[mt][0][r] = 1.f/(1.f + __expf(-(acc[mt][4][r] + bg0)));
                gacc[mt][1][r] = 1.f/(1.f + __expf(-(acc[mt][5][r] + bg1)));
            }
            *(int2*)(kfT + (size_t)(lm   )*ST_N + n0) = pk4(ep0[0],ep0[1],ep0[2],ep0[3]);
            *(int2*)(kfT + (size_t)(lm+32)*ST_N + n0) = pk4(em0[0],em0[1],em0[2],em0[3]);
            *(int2*)(kfT + (size_t)(lm+16)*ST_N + n0) = pk4(ep1[0],ep1[1],ep1[2],ep1[3]);
            *(int2*)(kfT + (size_t)(lm+48)*ST_N + n0) = pk4(em1[0],em1[1],em1[2],em1[3]);
            *(int2*)(vT  + (size_t)(lm   )*ST_N + n0) = pk4(v0[0],v0[1],v0[2],v0[3]);
            *(int2*)(vT  + (size_t)(16+lm)*ST_N + n0) = pk4(v1[0],v1[1],v1[2],v1[3]);
        }
    }
    __syncthreads();
    // ---- phase 2: kvT[d][f] = sum_n kfT[f][n]*vT[d][n]; ksum via ones-frag ----
    {
        f32x4 acc0=(f32x4){0,0,0,0}, acc1=(f32x4){0,0,0,0}, acc2=(f32x4){0,0,0,0};
        __builtin_amdgcn_s_setprio(1);
        #pragma unroll
        for(int ks=0; ks<8; ++ks){
            bh8 aa = ld_frag(kfT + (size_t)(wv*16+lm)*ST_N + ks*32 + quad*8);
            bh8 b0 = ld_frag(vT + (size_t)lm*ST_N      + ks*32 + quad*8);
            bh8 b1 = ld_frag(vT + (size_t)(16+lm)*ST_N + ks*32 + quad*8);
            acc0 = MFMA(aa, b0, acc0, 0,0,0);
            acc1 = MFMA(aa, b1, acc1, 0,0,0);
            acc2 = MFMA(aa, onesf, acc2, 0,0,0);
        }
        __builtin_amdgcn_s_setprio(0);
        int f0 = wv*16 + quad*4;
        *(int2*)(kvT + (size_t)(lm   )*ST_F + f0) = pk4(acc0[0],acc0[1],acc0[2],acc0[3]);
        *(int2*)(kvT + (size_t)(16+lm)*ST_F + f0) = pk4(acc1[0],acc1[1],acc1[2],acc1[3]);
        if(lm==0)
            *(int2*)(kvT + (size_t)32*ST_F + f0) = pk4(acc2[0],acc2[1],acc2[2],acc2[3]);
    }
    __syncthreads();
    // ---- qf epilogue (was phase 3's GEMM — now just bias+exp+stores) ----
    {
        float bb0 = bf2f(pb[P_CQB + h*32 + lm]);
        float bb1 = bf2f(pb[P_CQB + h*32 + 16 + lm]);
        #pragma unroll
        for(int mt=0; mt<4; ++mt)
            #pragma unroll
            for(int r=0; r<4; ++r){
                int n = wv*64 + mt*16 + quad*4 + r;
                float m0 = fminf(8.f, fmaxf(-8.f, qacc[mt][0][r] + bb0));
                float m1 = fminf(8.f, fmaxf(-8.f, qacc[mt][1][r] + bb1));
                u32 q0 = pk2h(__expf( m0), __expf(-m0));
                u32 q1 = pk2h(__expf( m1), __expf(-m1));
                qf[n*ST_F + lm     ] = (u16)q0;
                qf[n*ST_F + lm + 32] = (u16)(q0>>16);
                qf[n*ST_F + lm + 16] = (u16)q1;
                qf[n*ST_F + lm + 48] = (u16)(q1>>16);
            }
    }
    __syncthreads();
    // ---- phase 4: out = (qf·kvT^T)/den * gate ----
    {
        f32x4 acc[4][3];
        #pragma unroll
        for(int mt=0;mt<4;++mt)
            #pragma unroll
            for(int nt=0;nt<3;++nt) acc[mt][nt]=(f32x4){0,0,0,0};
        __builtin_amdgcn_s_setprio(1);
        #pragma unroll
        for(int ks=0; ks<2; ++ks){
            bh8 b0 = ld_frag(kvT + (size_t)lm*ST_F      + ks*32 + quad*8);
            bh8 b1 = ld_frag(kvT + (size_t)(16+lm)*ST_F + ks*32 + quad*8);
            bh8 b2 = ld_frag(kvT + (size_t)32*ST_F      + ks*32 + quad*8); // ksum, broadcast
            #pragma unroll
            for(int mt=0; mt<4; ++mt){
                bh8 aa = ld_frag(qf + (size_t)(wv*64+mt*16+lm)*ST_F + ks*32 + quad*8);
                acc[mt][0] = MFMA(aa, b0, acc[mt][0], 0,0,0);
                acc[mt][1] = MFMA(aa, b1, acc[mt][1], 0,0,0);
                acc[mt][2] = MFMA(aa, b2, acc[mt][2], 0,0,0);
            }
        }
        __builtin_amdgcn_s_setprio(0);
        #pragma unroll
        for(int mt=0; mt<4; ++mt)
            #pragma unroll
            for(int r=0; r<4; ++r){
                int n = wv*64 + mt*16 + quad*4 + r;
                float rcp = 1.f / fmaxf(acc[mt][2][r], 1e-6f);
                u16* op = attn + ((size_t)row*256 + n)*128 + h*32;
                u32 o = pk2h(acc[mt][0][r]*rcp*gacc[mt][0][r],
                             acc[mt][1][r]*rcp*gacc[mt][1][r]);
                op[lm]    = (u16)o;
                op[16+lm] = (u16)(o>>16);
            }
    }
}

// ---------------- MFMA o-proj: attn(bf16) -> out(f32), x mask — direct f32 stores ----------------
__global__ __launch_bounds__(256,2)
void oproj_kernel(const u16* __restrict__ attn, const u16* __restrict__ pb,
                  const int* __restrict__ mask, float* __restrict__ out){
    int tid = threadIdx.x;
    int lane = tid&63, wv = tid>>6;
    int mhalf = (wv>>1)*64, nhalf = (wv&1)*64;
    int lm = lane&15, quad = lane>>4;
    int m0 = blockIdx.x*128;

    f32x4 acc[4][4];
    #pragma unroll
    for(int mt=0;mt<4;++mt)
        #pragma unroll
        for(int nt=0;nt<4;++nt)
            acc[mt][nt] = (f32x4){0.f,0.f,0.f,0.f};

    const u16* Abase = attn + (size_t)(m0 + mhalf + lm)*128 + quad*8;
    const u16* W = pb + P_OW;
    #pragma unroll
    for(int ks=0; ks<4; ++ks){
        bh8 a[4], b[4];
        #pragma unroll
        for(int mt=0; mt<4; ++mt)
            a[mt] = ld_frag(Abase + (size_t)mt*16*128 + ks*32);
        #pragma unroll
        for(int nt=0; nt<4; ++nt)
            b[nt] = ld_frag(W + (size_t)(nhalf + nt*16 + lm)*128 + ks*32 + quad*8);
        #pragma unroll
        for(int mt=0; mt<4; ++mt)
            #pragma unroll
            for(int nt=0; nt<4; ++nt)
                acc[mt][nt] = MFMA(a[mt], b[nt], acc[mt][nt], 0, 0, 0);
    }
    float bv[4];
    #pragma unroll
    for(int nt=0; nt<4; ++nt) bv[nt] = bf2f(pb[P_OB + nhalf + nt*16 + lm]);
    #pragma unroll
    for(int mt=0; mt<4; ++mt){
        int mrow = m0 + mhalf + mt*16 + quad*4;
        float mk[4];
        #pragma unroll
        for(int r=0;r<4;++r) mk[r] = (float)mask[mrow+r];
        #pragma unroll
        for(int r=0; r<4; ++r){
            float* orow = out + (size_t)(mrow + r)*128 + nhalf + lm;
            #pragma unroll
            for(int nt=0; nt<4; ++nt)
                orow[nt*16] = (acc[mt][nt][r] + bv[nt]) * mk[r];
        }
    }
}

// ---------------- launch: 3 kernels ----------------
extern "C" void kernel_launch(void* const* d_in, const int* in_sizes, int n_in,
                              void* d_out, int out_size, void* d_ws, size_t ws_size,
                              hipStream_t stream){
    const float* z    = (const float*)d_in[0];
    const int*   mask = (const int*)d_in[1];

    char* ws = (char*)d_ws;
    const size_t MB = (size_t)1<<20;
    u16* zn   = (u16*)(ws + 0*MB);      // 16 MB [t][128] bf16
    u16* attn = (u16*)(ws + 16*MB);     // 16 MB [t][128] bf16
    u16* pb   = (u16*)(ws + 32*MB);     // ~231 KB bf16 param block

    prep_ln_kernel<<<NCONV+129+LN_BLOCKS,256,0,stream>>>(
        (const float*)d_in[2],  (const float*)d_in[3],  (const float*)d_in[4],  (const float*)d_in[5],
        (const float*)d_in[6],  (const float*)d_in[7],  (const float*)d_in[8],  (const float*)d_in[9],
        (const float*)d_in[10], (const float*)d_in[11], (const float*)d_in[12], (const float*)d_in[13],
        (const float*)d_in[14], (const float*)d_in[15], (const float*)d_in[16], (const float*)d_in[17],
        pb, z, zn);
    mega_kernel<<<1024,256,0,stream>>>(zn, mask, pb, attn);
    oproj_kernel<<<512,256,0,stream>>>(attn, pb, mask, (float*)d_out);
}

// Round 16
// 170.340 us; speedup vs baseline: 1.0335x; 1.0087x over previous
//
#include <hip/hip_runtime.h>
#include <hip/hip_bf16.h>
#include <stdint.h>

#define DEV __device__ __forceinline__

typedef unsigned short u16;
typedef unsigned int u32;
typedef short bh8 __attribute__((ext_vector_type(8)));
typedef float f32x4 __attribute__((ext_vector_type(4)));

// ---------- bf16 helpers ----------
DEV float bf2f(u16 v){ return __uint_as_float(((u32)v)<<16); }
DEV u16 f2bf(float f){
    u32 x = __float_as_uint(f);
    x += 0x7fffu + ((x>>16)&1u);
    return (u16)(x>>16);
}
// Hot-path conversions via hip_bf16 API (RNE, same rounding as f2bf; compiler
// lowers to v_cvt_pk_bf16_f32 — R13 verified: VALUBusy 32->28, no spill).
DEV u32 pk2h(float a, float b){
    float2 t; t.x = a; t.y = b;
    __hip_bfloat162 h = __float22bfloat162_rn(t);
    union{ __hip_bfloat162 h; u32 u; } c; c.h = h; return c.u;
}
DEV int2 pk4(float a, float b, float c, float d){
    int2 r;
    r.x = (int)pk2h(a, b);
    r.y = (int)pk2h(c, d);
    return r;
}
DEV bh8 ld_frag(const u16* p){
    int4 v = *(const int4*)p;
    union{ int4 i; bh8 h; } u; u.i = v; return u.h;
}
#define MFMA __builtin_amdgcn_mfma_f32_16x16x32_bf16

// Problem constants: BSZ=1, S=256, C=128, H=4, D=32, F=64. f32 I/O, bf16 internal.
//
// Session ledger:
//  R0: 4 kernels, mega 46.0, total 182.7
//  R1-R3,R11: occupancy chase: ALL slower. Not wave-count-bound.
//  R4: hand-written asm cvt_pk -> NaN. FAILED (API casts fine, R13).
//  R5/R6/R7/R9/R10: five LN-fusion variants failed. ln stays separate.
//  R8: prep if-chain + oproj direct-store: mega 45.1, total 175.8
//  R12: prep+ln merged, ln grid-strided: total 174.4.
//  R13: cvt_pk epilogues + setprio: VALUBusy 32->28, time unchanged. Not VALU-bound.
//  R14: XCD swizzle: FETCH 33.6->9.0MB, mega time unchanged 44.5. Not fetch-bound.
//  R15: SPLIT RESULT. (a) phase-3-fold into stage A: mega 44.5->64.6 REGRESSED
//      (8 acc columns strangled scheduling at 128 VGPR; no spill but MfmaUtil
//      9.5->6.5) -> reverted. (b) LN loop un-serialized: non-mega pool -20us
//      -> kept. total 171.8 (best).
//  R16 (this): pure recombination — mega = exact R14 body (44.5us proven),
//      prep_ln = R15 (unrolled LN). Predict total ~150-155.

// Param block layout (elements, bf16) inside workspace:
#define P_LNW 0
#define P_LNB 128
#define P_QW  256
#define P_QB  16640
#define P_KW  16768
#define P_KB  33152
#define P_VW  33280
#define P_VB  49664
#define P_QFW 49792
#define P_QFB 50816
#define P_KFW 50848
#define P_KFB 51872
#define P_GW  51904
#define P_GB  68288
#define P_OW  68416
#define P_OB  84800
#define P_TOT 84928
#define P_CQW 84928    // [h][j][c] 4*32*128
#define P_CQB 101312   // [h][j]    4*32
#define P_CKW 101440
#define P_CKB 117824

#define NCONV 332
#define LN_BLOCKS 2048     // 2048 blocks x 32 tokens = 65536 tokens

// ---------------- prep + LN merged (independent work, one launch) ----------------
__global__ void prep_ln_kernel(
    const float* p0, const float* p1, const float* p2, const float* p3,
    const float* p4, const float* p5, const float* p6, const float* p7,
    const float* p8, const float* p9, const float* p10, const float* p11,
    const float* p12, const float* p13, const float* p14, const float* p15,
    u16* __restrict__ dst,
    const float* __restrict__ z, u16* __restrict__ zn){
    int b = blockIdx.x, tid = threadIdx.x;
    if(b < NCONV){
        int idx = b*256 + tid;
        if(idx >= P_TOT) return;
        // if-chain (cndmask), NOT runtime-indexed local arrays (rule #20 -> scratch).
        const float* sp = p0; int base = P_LNW;
        if(idx >= P_LNB){ sp = p1;  base = P_LNB; }
        if(idx >= P_QW ){ sp = p2;  base = P_QW;  }
        if(idx >= P_QB ){ sp = p3;  base = P_QB;  }
        if(idx >= P_KW ){ sp = p4;  base = P_KW;  }
        if(idx >= P_KB ){ sp = p5;  base = P_KB;  }
        if(idx >= P_VW ){ sp = p6;  base = P_VW;  }
        if(idx >= P_VB ){ sp = p7;  base = P_VB;  }
        if(idx >= P_QFW){ sp = p8;  base = P_QFW; }
        if(idx >= P_QFB){ sp = p9;  base = P_QFB; }
        if(idx >= P_KFW){ sp = p10; base = P_KFW; }
        if(idx >= P_KFB){ sp = p11; base = P_KFB; }
        if(idx >= P_GW ){ sp = p12; base = P_GW;  }
        if(idx >= P_GB ){ sp = p13; base = P_GB;  }
        if(idx >= P_OW ){ sp = p14; base = P_OW;  }
        if(idx >= P_OB ){ sp = p15; base = P_OB;  }
        dst[idx] = f2bf(sp[idx - base]);
    } else if(b < NCONV + 128){
        // combined weights: Wc[h][j][c] = sum_d F[j][d] * W[h*32+d][c]
        int idx = (b - NCONV)*256 + tid;            // [0, 32768)
        int sel = idx >> 14;
        int rem = idx & 16383;
        int h = rem >> 12, j = (rem >> 7) & 31, c = rem & 127;
        const float* FWp = sel ? p10 : p8;
        const float* Wp  = sel ? p4  : p2;
        float s = 0.f;
        #pragma unroll
        for(int d=0; d<32; ++d)
            s += FWp[j*32+d] * Wp[(h*32+d)*128 + c];
        dst[(sel ? P_CKW : P_CQW) + h*4096 + j*128 + c] = f2bf(s);
    } else if(b == NCONV + 128){
        // combined biases: bc[h][j] = sum_d F[j][d]*b[h*32+d] + fb[j]
        int t = tid;
        int sel = t >> 7, h = (t >> 5) & 3, j = t & 31;
        const float* FWp = sel ? p10 : p8;
        const float* FBp = sel ? p11 : p9;
        const float* Bp  = sel ? p5  : p3;
        float s = FBp[j];
        #pragma unroll
        for(int d=0; d<32; ++d)
            s += FWp[j*32+d] * Bp[h*32+d];
        dst[(sel ? P_CKB : P_CQB) + h*32 + j] = f2bf(s);
    } else {
        // ---- LayerNorm, grid-strided: 32 tokens/block, 8 per wave ----
        // R15-verified: UNROLLED token loop (compiler pipelines the 8 HBM loads)
        // was worth ~20us vs the serialized form. Keep.
        int lb = b - (NCONV + 129);                 // [0, LN_BLOCKS)
        int lane = tid & 63, wv = tid >> 6;
        int c0 = 2*lane;
        float w0 = p0[c0], w1 = p0[c0+1];
        float b0 = p1[c0], b1 = p1[c0+1];
        #pragma unroll
        for(int it=0; it<8; ++it){
            int t = lb*32 + it*4 + wv;
            float2 v = ((const float2*)z)[(size_t)t*64 + lane];
            float x0 = v.x, x1 = v.y;
            float s = x0 + x1, s2 = x0*x0 + x1*x1;
            #pragma unroll
            for(int o=1;o<64;o<<=1){ s += __shfl_xor(s,o,64); s2 += __shfl_xor(s2,o,64); }
            float mean = s*(1.f/128.f);
            float var  = s2*(1.f/128.f) - mean*mean;
            float rs = rsqrtf(var + 1e-5f);
            float o0 = (x0-mean)*rs*w0 + b0;
            float o1 = (x1-mean)*rs*w1 + b1;
            u32 po = (u32)f2bf(o0) | ((u32)f2bf(o1)<<16);
            *(u32*)(zn + (size_t)t*128 + c0) = po;
        }
    }
}

// ---------------- mega kernel: one block per (row, head), XCD-swizzled [exact R14 body] ----------------
// LDS (bytes):
//   mask_f [256 f32]      @ 0       (1024)
//   kfT    [64][264] u16  @ 1024    (33792)  kf^T [f][n], masked
//   vT     [32][264] u16  @ 34816   (16896)  v^T [d][n] masked
//   qf     [256][68] u16  @ 1024    (34816)  aliases kfT(+vT head); [n][f]
//   kvT    [33][68]  u16  @ 51712   (4488)   kv^T [d][f]; row 32 = ksum
#define ST_N 264
#define ST_F 68
#define SM_KF   1024
#define SM_VT   34816
#define SM_QF   1024
#define SM_KVT  51712
#define SM_TOT  56200

__global__ __launch_bounds__(256,2)
void mega_kernel(const u16* __restrict__ zn, const int* __restrict__ mask,
                 const u16* __restrict__ pb, u16* __restrict__ attn){
    __shared__ __align__(16) char smem[SM_TOT];
    float* mask_f = (float*)smem;
    u16* kfT = (u16*)(smem + SM_KF);
    u16* vT  = (u16*)(smem + SM_VT);
    u16* qf  = (u16*)(smem + SM_QF);
    u16* kvT = (u16*)(smem + SM_KVT);

    // XCD swizzle (R14-verified: FETCH 33.6->9.0MB). Bijective on [0,1024).
    int g = blockIdx.x;
    int u = (g & 7)*128 + (g >> 3);
    int row = u >> 2, h = u & 3;
    int tid = threadIdx.x, lane = tid & 63, wv = tid >> 6;
    int lm = lane & 15, quad = lane >> 4;

    mask_f[tid] = (float)mask[row*256 + tid];

    // zn A-frags: loaded once, reused by phases 1 and 3
    bh8 a[4][4];
    {
        const u16* Ab = zn + ((size_t)row*256 + wv*64 + lm)*128 + quad*8;
        #pragma unroll
        for(int mt=0; mt<4; ++mt)
            #pragma unroll
            for(int ks=0; ks<4; ++ks)
                a[mt][ks] = ld_frag(Ab + (size_t)mt*16*128 + ks*32);
    }
    bh8 onesf;
    { union{int4 i; bh8 hh;} uo; uo.i.x=uo.i.y=uo.i.z=uo.i.w=0x3F803F80; onesf = uo.hh; }

    __syncthreads();

    f32x4 gacc[4][2];
    // ---- phase 1 (merged): B = [ck0 ck1 | v0 v1 | g0 g1], shared A ----
    {
        f32x4 acc[4][6];
        #pragma unroll
        for(int mt=0;mt<4;++mt)
            #pragma unroll
            for(int j=0;j<6;++j) acc[mt][j] = (f32x4){0,0,0,0};
        __builtin_amdgcn_s_setprio(1);
        #pragma unroll
        for(int ks=0; ks<4; ++ks){
            bh8 b[6];
            b[0] = ld_frag(pb + P_CKW + h*4096 + lm*128            + ks*32 + quad*8);
            b[1] = ld_frag(pb + P_CKW + h*4096 + (16+lm)*128       + ks*32 + quad*8);
            b[2] = ld_frag(pb + P_VW + (size_t)(h*32 + lm)*128     + ks*32 + quad*8);
            b[3] = ld_frag(pb + P_VW + (size_t)(h*32 + 16+lm)*128  + ks*32 + quad*8);
            b[4] = ld_frag(pb + P_GW + (size_t)(h*32 + lm)*128     + ks*32 + quad*8);
            b[5] = ld_frag(pb + P_GW + (size_t)(h*32 + 16+lm)*128  + ks*32 + quad*8);
            #pragma unroll
            for(int mt=0; mt<4; ++mt)
                #pragma unroll
                for(int j=0;j<6;++j)
                    acc[mt][j] = MFMA(a[mt][ks], b[j], acc[mt][j], 0,0,0);
        }
        __builtin_amdgcn_s_setprio(0);
        float bk0 = bf2f(pb[P_CKB + h*32 + lm]);
        float bk1 = bf2f(pb[P_CKB + h*32 + 16 + lm]);
        float bv0 = bf2f(pb[P_VB + h*32 + lm]);
        float bv1 = bf2f(pb[P_VB + h*32 + 16 + lm]);
        float bg0 = bf2f(pb[P_GB + h*32 + lm]);
        float bg1 = bf2f(pb[P_GB + h*32 + 16 + lm]);
        #pragma unroll
        for(int mt=0; mt<4; ++mt){
            int n0 = wv*64 + mt*16 + quad*4;
            float ep0[4], em0[4], ep1[4], em1[4], v0[4], v1[4];
            #pragma unroll
            for(int r=0; r<4; ++r){
                float mk = mask_f[n0+r];
                float m0 = fminf(8.f, fmaxf(-8.f, acc[mt][0][r] + bk0));
                float m1 = fminf(8.f, fmaxf(-8.f, acc[mt][1][r] + bk1));
                ep0[r] = __expf( m0)*mk;  em0[r] = __expf(-m0)*mk;
                ep1[r] = __expf( m1)*mk;  em1[r] = __expf(-m1)*mk;
                v0[r] = (acc[mt][2][r] + bv0)*mk;
                v1[r] = (acc[mt][3][r] + bv1)*mk;
                gacc[mt][0][r] = 1.f/(1.f + __expf(-(acc[mt][4][r] + bg0)));
                gacc[mt][1][r] = 1.f/(1.f + __expf(-(acc[mt][5][r] + bg1)));
            }
            *(int2*)(kfT + (size_t)(lm   )*ST_N + n0) = pk4(ep0[0],ep0[1],ep0[2],ep0[3]);
            *(int2*)(kfT + (size_t)(lm+32)*ST_N + n0) = pk4(em0[0],em0[1],em0[2],em0[3]);
            *(int2*)(kfT + (size_t)(lm+16)*ST_N + n0) = pk4(ep1[0],ep1[1],ep1[2],ep1[3]);
            *(int2*)(kfT + (size_t)(lm+48)*ST_N + n0) = pk4(em1[0],em1[1],em1[2],em1[3]);
            *(int2*)(vT  + (size_t)(lm   )*ST_N + n0) = pk4(v0[0],v0[1],v0[2],v0[3]);
            *(int2*)(vT  + (size_t)(16+lm)*ST_N + n0) = pk4(v1[0],v1[1],v1[2],v1[3]);
        }
    }
    __syncthreads();
    // ---- phase 2: kvT[d][f] = sum_n kfT[f][n]*vT[d][n]; ksum via ones-frag ----
    {
        f32x4 acc0=(f32x4){0,0,0,0}, acc1=(f32x4){0,0,0,0}, acc2=(f32x4){0,0,0,0};
        __builtin_amdgcn_s_setprio(1);
        #pragma unroll
        for(int ks=0; ks<8; ++ks){
            bh8 aa = ld_frag(kfT + (size_t)(wv*16+lm)*ST_N + ks*32 + quad*8);
            bh8 b0 = ld_frag(vT + (size_t)lm*ST_N      + ks*32 + quad*8);
            bh8 b1 = ld_frag(vT + (size_t)(16+lm)*ST_N + ks*32 + quad*8);
            acc0 = MFMA(aa, b0, acc0, 0,0,0);
            acc1 = MFMA(aa, b1, acc1, 0,0,0);
            acc2 = MFMA(aa, onesf, acc2, 0,0,0);
        }
        __builtin_amdgcn_s_setprio(0);
        int f0 = wv*16 + quad*4;
        *(int2*)(kvT + (size_t)(lm   )*ST_F + f0) = pk4(acc0[0],acc0[1],acc0[2],acc0[3]);
        *(int2*)(kvT + (size_t)(16+lm)*ST_F + f0) = pk4(acc1[0],acc1[1],acc1[2],acc1[3]);
        if(lm==0)
            *(int2*)(kvT + (size_t)32*ST_F + f0) = pk4(acc2[0],acc2[1],acc2[2],acc2[3]);
    }
    __syncthreads();
    // ---- phase 3: qf[n][f] = featmap(zn·Wc_q^T + bc_q)  (aliases kfT/vT) ----
    {
        f32x4 acc[4][2];
        #pragma unroll
        for(int mt=0;mt<4;++mt){ acc[mt][0]=(f32x4){0,0,0,0}; acc[mt][1]=(f32x4){0,0,0,0}; }
        __builtin_amdgcn_s_setprio(1);
        #pragma unroll
        for(int ks=0; ks<4; ++ks){
            bh8 b0 = ld_frag(pb + P_CQW + h*4096 + lm*128      + ks*32 + quad*8);
            bh8 b1 = ld_frag(pb + P_CQW + h*4096 + (16+lm)*128 + ks*32 + quad*8);
            #pragma unroll
            for(int mt=0; mt<4; ++mt){
                acc[mt][0] = MFMA(a[mt][ks], b0, acc[mt][0], 0,0,0);
                acc[mt][1] = MFMA(a[mt][ks], b1, acc[mt][1], 0,0,0);
            }
        }
        __builtin_amdgcn_s_setprio(0);
        float bb0 = bf2f(pb[P_CQB + h*32 + lm]);
        float bb1 = bf2f(pb[P_CQB + h*32 + 16 + lm]);
        #pragma unroll
        for(int mt=0; mt<4; ++mt)
            #pragma unroll
            for(int r=0; r<4; ++r){
                int n = wv*64 + mt*16 + quad*4 + r;
                float m0 = fminf(8.f, fmaxf(-8.f, acc[mt][0][r] + bb0));
                float m1 = fminf(8.f, fmaxf(-8.f, acc[mt][1][r] + bb1));
                u32 q0 = pk2h(__expf( m0), __expf(-m0));
                u32 q1 = pk2h(__expf( m1), __expf(-m1));
                qf[n*ST_F + lm     ] = (u16)q0;
                qf[n*ST_F + lm + 32] = (u16)(q0>>16);
                qf[n*ST_F + lm + 16] = (u16)q1;
                qf[n*ST_F + lm + 48] = (u16)(q1>>16);
            }
    }
    __syncthreads();
    // ---- phase 4: out = (qf·kvT^T)/den * gate ----
    {
        f32x4 acc[4][3];
        #pragma unroll
        for(int mt=0;mt<4;++mt)
            #pragma unroll
            for(int nt=0;nt<3;++nt) acc[mt][nt]=(f32x4){0,0,0,0};
        __builtin_amdgcn_s_setprio(1);
        #pragma unroll
        for(int ks=0; ks<2; ++ks){
            bh8 b0 = ld_frag(kvT + (size_t)lm*ST_F      + ks*32 + quad*8);
            bh8 b1 = ld_frag(kvT + (size_t)(16+lm)*ST_F + ks*32 + quad*8);
            bh8 b2 = ld_frag(kvT + (size_t)32*ST_F      + ks*32 + quad*8); // ksum, broadcast
            #pragma unroll
            for(int mt=0; mt<4; ++mt){
                bh8 aa = ld_frag(qf + (size_t)(wv*64+mt*16+lm)*ST_F + ks*32 + quad*8);
                acc[mt][0] = MFMA(aa, b0, acc[mt][0], 0,0,0);
                acc[mt][1] = MFMA(aa, b1, acc[mt][1], 0,0,0);
                acc[mt][2] = MFMA(aa, b2, acc[mt][2], 0,0,0);
            }
        }
        __builtin_amdgcn_s_setprio(0);
        #pragma unroll
        for(int mt=0; mt<4; ++mt)
            #pragma unroll
            for(int r=0; r<4; ++r){
                int n = wv*64 + mt*16 + quad*4 + r;
                float rcp = 1.f / fmaxf(acc[mt][2][r], 1e-6f);
                u16* op = attn + ((size_t)row*256 + n)*128 + h*32;
                u32 o = pk2h(acc[mt][0][r]*rcp*gacc[mt][0][r],
                             acc[mt][1][r]*rcp*gacc[mt][1][r]);
                op[lm]    = (u16)o;
                op[16+lm] = (u16)(o>>16);
            }
    }
}

// ---------------- MFMA o-proj: attn(bf16) -> out(f32), x mask — direct f32 stores ----------------
__global__ __launch_bounds__(256,2)
void oproj_kernel(const u16* __restrict__ attn, const u16* __restrict__ pb,
                  const int* __restrict__ mask, float* __restrict__ out){
    int tid = threadIdx.x;
    int lane = tid&63, wv = tid>>6;
    int mhalf = (wv>>1)*64, nhalf = (wv&1)*64;
    int lm = lane&15, quad = lane>>4;
    int m0 = blockIdx.x*128;

    f32x4 acc[4][4];
    #pragma unroll
    for(int mt=0;mt<4;++mt)
        #pragma unroll
        for(int nt=0;nt<4;++nt)
            acc[mt][nt] = (f32x4){0.f,0.f,0.f,0.f};

    const u16* Abase = attn + (size_t)(m0 + mhalf + lm)*128 + quad*8;
    const u16* W = pb + P_OW;
    #pragma unroll
    for(int ks=0; ks<4; ++ks){
        bh8 a[4], b[4];
        #pragma unroll
        for(int mt=0; mt<4; ++mt)
            a[mt] = ld_frag(Abase + (size_t)mt*16*128 + ks*32);
        #pragma unroll
        for(int nt=0; nt<4; ++nt)
            b[nt] = ld_frag(W + (size_t)(nhalf + nt*16 + lm)*128 + ks*32 + quad*8);
        #pragma unroll
        for(int mt=0; mt<4; ++mt)
            #pragma unroll
            for(int nt=0; nt<4; ++nt)
                acc[mt][nt] = MFMA(a[mt], b[nt], acc[mt][nt], 0, 0, 0);
    }
    float bv[4];
    #pragma unroll
    for(int nt=0; nt<4; ++nt) bv[nt] = bf2f(pb[P_OB + nhalf + nt*16 + lm]);
    #pragma unroll
    for(int mt=0; mt<4; ++mt){
        int mrow = m0 + mhalf + mt*16 + quad*4;
        float mk[4];
        #pragma unroll
        for(int r=0;r<4;++r) mk[r] = (float)mask[mrow+r];
        #pragma unroll
        for(int r=0; r<4; ++r){
            float* orow = out + (size_t)(mrow + r)*128 + nhalf + lm;
            #pragma unroll
            for(int nt=0; nt<4; ++nt)
                orow[nt*16] = (acc[mt][nt][r] + bv[nt]) * mk[r];
        }
    }
}

// ---------------- launch: 3 kernels ----------------
extern "C" void kernel_launch(void* const* d_in, const int* in_sizes, int n_in,
                              void* d_out, int out_size, void* d_ws, size_t ws_size,
                              hipStream_t stream){
    const float* z    = (const float*)d_in[0];
    const int*   mask = (const int*)d_in[1];

    char* ws = (char*)d_ws;
    const size_t MB = (size_t)1<<20;
    u16* zn   = (u16*)(ws + 0*MB);      // 16 MB [t][128] bf16
    u16* attn = (u16*)(ws + 16*MB);     // 16 MB [t][128] bf16
    u16* pb   = (u16*)(ws + 32*MB);     // ~231 KB bf16 param block

    prep_ln_kernel<<<NCONV+129+LN_BLOCKS,256,0,stream>>>(
        (const float*)d_in[2],  (const float*)d_in[3],  (const float*)d_in[4],  (const float*)d_in[5],
        (const float*)d_in[6],  (const float*)d_in[7],  (const float*)d_in[8],  (const float*)d_in[9],
        (const float*)d_in[10], (const float*)d_in[11], (const float*)d_in[12], (const float*)d_in[13],
        (const float*)d_in[14], (const float*)d_in[15], (const float*)d_in[16], (const float*)d_in[17],
        pb, z, zn);
    mega_kernel<<<1024,256,0,stream>>>(zn, mask, pb, attn);
    oproj_kernel<<<512,256,0,stream>>>(attn, pb, mask, (float*)d_out);
}